// Round 11
// baseline (95.924 us; speedup 1.0000x reference)
//
#include <hip/hip_runtime.h>
#include <hip/hip_bf16.h>
#include <cstdint>

#define BATCH 8192
#define DIM   128
#define KAUG  160          // 128 data + 10 label dims + 22 zero pad
#define MARGIN 1.0f
#define SEP    8192.0f     // 2 * 64^2 label separator (exact in fp32/bf16)

typedef __attribute__((ext_vector_type(8))) short short8;
typedef __attribute__((ext_vector_type(4))) float f32x4;

// async 16B global -> LDS; LDS dst = wave-uniform base, HW adds lane*16
__device__ __forceinline__ void async_copy16(const void* g, void* lds) {
    __builtin_amdgcn_global_load_lds(
        (const __attribute__((address_space(1))) unsigned int*)g,
        (__attribute__((address_space(3))) unsigned int*)lds, 16, 0, 0);
}

// ---------------------------------------------------------------------------
// Kernel 1: build label-AUGMENTED bf16 matrices (validated R10, absmax 0):
//   EbfA row i: [bf16(e_i), +64*onehot(lab_i), 0...]   (160 dims)
//   EbfB row j: [bf16(e_j), -64*onehot(lab_j), 0...]
//   val = sqj - 2*dot_aug = (sqj - 2*dot) + 8192*[same] -> label selection is
//   pure max/min in the epilogue (3 VALU/pair, no label loads).
// ---------------------------------------------------------------------------
__global__ __launch_bounds__(256) void bhtl_prep(
    const float* __restrict__ emb,
    const int* __restrict__ labels,
    __hip_bfloat16* __restrict__ EbfA,
    __hip_bfloat16* __restrict__ EbfB,
    float* __restrict__ sq,
    unsigned* __restrict__ hp2,
    unsigned* __restrict__ hn2)
{
    const int w   = threadIdx.x >> 6;
    const int l   = threadIdx.x & 63;
    const int row = blockIdx.x * 4 + w;
    const float2 e = ((const float2*)(emb + row * DIM))[l];
    __hip_bfloat162 h2;
    h2.x = __float2bfloat16(e.x);
    h2.y = __float2bfloat16(e.y);
    ((__hip_bfloat162*)(EbfA + (size_t)row * KAUG))[l] = h2;
    ((__hip_bfloat162*)(EbfB + (size_t)row * KAUG))[l] = h2;
    if (l < 16) {   // augmented dims 128 + 2l, 129 + 2l
        const int lab = labels[row];
        const float a0 = (2 * l     == lab) ? 64.f : 0.f;
        const float a1 = (2 * l + 1 == lab) ? 64.f : 0.f;
        __hip_bfloat162 hA, hB;
        hA.x = __float2bfloat16(a0);  hA.y = __float2bfloat16(a1);
        hB.x = __float2bfloat16(-a0); hB.y = __float2bfloat16(-a1);
        ((__hip_bfloat162*)(EbfA + (size_t)row * KAUG + DIM))[l] = hA;
        ((__hip_bfloat162*)(EbfB + (size_t)row * KAUG + DIM))[l] = hB;
    }
    float s = e.x * e.x + e.y * e.y;
    #pragma unroll
    for (int d = 1; d < 64; d <<= 1) s += __shfl_xor(s, d, 64);
    if (l == 0) {
        sq[row]  = s;
        hp2[row] = 0u;           // max accumulator (clamped non-negative)
        hn2[row] = 0x7F800000u;  // +inf (min accumulator)
    }
}

// ---------------------------------------------------------------------------
// Kernel 2: fused augmented E_A @ E_B^T + max/min epilogue.
// BLOCK-SHARED depth-4 pipeline with RAW barriers:
//   1024 blocks = 64 row-tiles x 16 col-splits, 128 threads (2 waves).
//   Block: 128 rows x 512 cols; both waves consume the SAME 16-col chunks
//   (32 of them) from 5 shared LDS buffers -> staging traffic HALVED vs
//   wave-private (164 MB total), per-XCD B slice ~320 KB = L2-local.
//   Producer parity: chunk c staged (5 glds) by wave c%2 at iter c-4
//   (depth-4 ~ 4 iters in flight, covers IC latency).
//   Raw `s_barrier` via asm (compiler's __syncthreads would prepend
//   vmcnt(0) = the m97 drain). Ordering discipline:
//     - producer executes s_waitcnt vmcnt(5) BEFORE barrier i (leaves only
//       chunk i+2's 5 glds outstanding => chunk i complete);
//     - consumers need no vm wait (barrier + producer's wait orders LDS);
//     - 5 buffers: writes for chunk i+4 issue after barrier i, reads of
//       chunk i-1 (same buffer) retired before barrier i => no WAR race;
//     - tail iters 30,31: producer has nothing newer outstanding => vmcnt(0).
// Transposed MFMA (validated R4-R10): acc = mfma(B, A); lane (q,ln) elem r
//   -> row = rowbase + m*16 + ln, col = jbase + i*16 + q*4 + r.
// LDS 27.6 KB -> 4 blocks/CU, 8 waves/CU. Atomics fire-and-forget, NO fence.
// ---------------------------------------------------------------------------
__global__ __launch_bounds__(128) void bhtl_main(
    const __hip_bfloat16* __restrict__ EbfA,
    const __hip_bfloat16* __restrict__ EbfB,
    const float* __restrict__ sq,
    unsigned* __restrict__ hp2,
    unsigned* __restrict__ hn2)
{
    __shared__ __align__(16) unsigned short B_s[5][2560];  // 5 bufs x 5 KB
    __shared__ __align__(16) float sqm[512];               // col sq (block)

    const int tid  = threadIdx.x;
    const int w    = tid >> 6;
    const int lane = tid & 63;
    const int q    = lane >> 4;
    const int ln   = lane & 15;
    const int rt   = blockIdx.x >> 4;          // 0..63 row tile (128 rows)
    const int js   = blockIdx.x & 15;          // 0..15 col split (512 cols)
    const int rowbase = rt * 128 + w * 64;
    const int jbase   = js * 512;

    // ---- B chunk stager: 16 cols x 320 B = 320 units = 5 glds ----
    auto stageB = [&](int buf, int ch) {
        const int jb = jbase + ch * 16;
        #pragma unroll
        for (int c = 0; c < 5; ++c) {
            int U   = c * 64 + lane;           // 0..319
            int col = U / 20;                  // 0..15 (magic-mul)
            int u   = U - col * 20;            // 0..19
            int g   = (u < 16) ? (u ^ (col & 7)) : u;   // global-side swizzle
            async_copy16(EbfB + (size_t)(jb + col) * KAUG + g * 8,
                         &B_s[buf][c * 512]);
        }
    };

    // ---- A fragments (64 rows/wave, K=160), pinned in 80 VGPRs ----
    short8 af[4][5];
    float  sqi[4];
    #pragma unroll
    for (int m = 0; m < 4; ++m) {
        const int row = rowbase + m * 16 + ln;
        #pragma unroll
        for (int kc = 0; kc < 5; ++kc) {
            af[m][kc] = *(const short8*)(EbfA + (size_t)row * KAUG + kc * 32 + q * 8);
            asm("" : "+v"(af[m][kc]));
        }
        sqi[m] = sq[row];
    }

    // ---- prologue staging: wave0 -> sqm + chunks 0,2; wave1 -> chunks 1,3 ----
    if (w == 0) {
        async_copy16(sq + jbase +       lane * 4, &sqm[0]);
        async_copy16(sq + jbase + 256 + lane * 4, &sqm[256]);
    }
    stageB(w,     w);         // chunk w     -> buf w
    stageB(w + 2, w + 2);     // chunk w+2   -> buf w+2
    asm volatile("s_waitcnt vmcnt(0)" ::: "memory");
    asm volatile("s_barrier" ::: "memory");

    float mp[4] = {-INFINITY, -INFINITY, -INFINITY, -INFINITY};
    float mn[4] = { INFINITY,  INFINITY,  INFINITY,  INFINITY};

    auto doIter = [&](int i, int buf, int par, bool doStage, int stageBuf,
                      bool finalWait) {
        if (par == w) {        // producer of chunk i: guarantee it landed
            if (finalWait) asm volatile("s_waitcnt vmcnt(0)" ::: "memory");
            else           asm volatile("s_waitcnt vmcnt(5)" ::: "memory");
        }
        asm volatile("s_barrier" ::: "memory");

        short8 bfr[5];
        #pragma unroll
        for (int kc = 0; kc < 5; ++kc) {
            const int t    = kc * 4 + q;
            const int unit = (kc < 4) ? (t ^ (ln & 7)) : t;
            bfr[kc] = *(const short8*)(&B_s[buf][(ln * 20 + unit) * 8]);
        }
        f32x4 sqj = *(const f32x4*)(&sqm[i * 16 + q * 4]);

        if (doStage && par == w) stageB(stageBuf, i + 4);

        f32x4 acc[4];
        const f32x4 zero = {0.f, 0.f, 0.f, 0.f};
        #pragma unroll
        for (int m = 0; m < 4; ++m) acc[m] = zero;
        #pragma unroll
        for (int kc = 0; kc < 5; ++kc)
            #pragma unroll
            for (int m = 0; m < 4; ++m)
                acc[m] = __builtin_amdgcn_mfma_f32_16x16x32_bf16(
                    bfr[kc], af[m][kc], acc[m], 0, 0, 0);   // transposed

        #pragma unroll
        for (int m = 0; m < 4; ++m)
            #pragma unroll
            for (int r = 0; r < 4; ++r) {
                float val = fmaf(-2.0f, acc[m][r], sqj[r]);
                mp[m] = fmaxf(mp[m], val);
                mn[m] = fminf(mn[m], val);
            }
    };

    // iters 0..29 in unrolled groups of 10 (base % 10 == 0 -> buf = k%5,
    // parity = k&1 are compile-time after unroll). Stage while i+4 <= 31.
    #pragma unroll 1
    for (int base = 0; base < 30; base += 10) {
        #pragma unroll
        for (int k = 0; k < 10; ++k) {
            const int i = base + k;
            doIter(i, k % 5, k & 1, i <= 27, (k + 4) % 5, false);
        }
    }
    doIter(30, 0, 0, false, 0, true);   // producer w0: only chunk 30 left -> vmcnt(0)
    doIter(31, 1, 1, false, 0, true);   // producer w1: only chunk 31 left -> vmcnt(0)

    // ---- reduce over the 4 q-lanes sharing each row, then atomics ----
    #pragma unroll
    for (int m = 0; m < 4; ++m) {
        float a = mp[m], b = mn[m];
        a = fmaxf(a, __shfl_xor(a, 16, 64));
        a = fmaxf(a, __shfl_xor(a, 32, 64));
        b = fminf(b, __shfl_xor(b, 16, 64));
        b = fminf(b, __shfl_xor(b, 32, 64));
        if (q == 0) {
            const int row = rowbase + m * 16 + ln;
            // hp^2 = sqi + max - SEP; hn^2 = sqi + min; clamp>=0 (uint order
            // == float order; slices w/o same-class col self-correct to 0)
            atomicMax(&hp2[row], __float_as_uint(fmaxf(sqi[m] + a - SEP, 0.0f)));
            atomicMin(&hn2[row], __float_as_uint(fmaxf(sqi[m] + b, 0.0f)));
        }
    }
}

// ---------------------------------------------------------------------------
// Kernel 3: per-anchor loss + mean. Single block, deterministic output.
// ---------------------------------------------------------------------------
__global__ __launch_bounds__(1024) void bhtl_final(
    const unsigned* __restrict__ hp2,
    const unsigned* __restrict__ hn2,
    float* __restrict__ out)
{
    __shared__ float red[16];
    float sum = 0.f;
    for (int i = threadIdx.x; i < BATCH; i += 1024) {
        float hp = sqrtf(__uint_as_float(hp2[i]));
        float hn = sqrtf(__uint_as_float(hn2[i]));
        sum += fmaxf(hp - hn + MARGIN, 0.f);
    }
    #pragma unroll
    for (int d = 1; d < 64; d <<= 1) sum += __shfl_xor(sum, d, 64);
    int wv = threadIdx.x >> 6;
    if ((threadIdx.x & 63) == 0) red[wv] = sum;
    __syncthreads();
    if (threadIdx.x < 64) {
        float v = (threadIdx.x < 16) ? red[threadIdx.x] : 0.f;
        #pragma unroll
        for (int d = 1; d < 16; d <<= 1) v += __shfl_xor(v, d, 64);
        if (threadIdx.x == 0) out[0] = v / (float)BATCH;
    }
}

// ---------------------------------------------------------------------------
extern "C" void kernel_launch(void* const* d_in, const int* in_sizes, int n_in,
                              void* d_out, int out_size, void* d_ws, size_t ws_size,
                              hipStream_t stream)
{
    const float* emb    = (const float*)d_in[0];
    const int*   labels = (const int*)d_in[1];
    float*       out    = (float*)d_out;

    char* ws = (char*)d_ws;
    __hip_bfloat16* EbfA = (__hip_bfloat16*)ws;                       // 2.56 MiB
    __hip_bfloat16* EbfB = (__hip_bfloat16*)(ws + 3  * 1024 * 1024);  // 2.56 MiB
    float*    sq   = (float*)   (ws + 6 * 1024 * 1024);               // 32 KiB
    unsigned* hp2  = (unsigned*)(ws + 6 * 1024 * 1024 + 32 * 1024);   // 32 KiB
    unsigned* hn2  = (unsigned*)(ws + 6 * 1024 * 1024 + 64 * 1024);   // 32 KiB

    bhtl_prep<<<BATCH / 4, 256, 0, stream>>>(emb, labels, EbfA, EbfB, sq, hp2, hn2);
    bhtl_main<<<1024, 128, 0, stream>>>(EbfA, EbfB, sq, hp2, hn2);
    bhtl_final<<<1, 1024, 0, stream>>>(hp2, hn2, out);
}